// Round 1
// baseline (6509.199 us; speedup 1.0000x reference)
//
#include <hip/hip_runtime.h>
#include <hip/hip_bf16.h>

// CTRNN: T=1000, B=256, I=128, N=512, ALPHA=0.2
// d_in: x[1000,256,128] f32, h0[256,512] f32, W_in[512,128] f32, b_in[512] f32, W_hh[512,512] f32
// d_out: output[1000,256,512] f32 ++ hidden[256,512] f32
//
// Plan:
//  pack_kernel : W_hh -> bf16 MFMA-A-fragment layout (512KB) ; W_in -> hi/lo bf16 frags (2x128KB) in d_ws
//  xproj_kernel: xproj = x @ W_in^T + b_in via 3-term split-bf16 MFMA, written INTO d_out
//  scan_kernel : 16 WGs (one per 16-batch tile), W_hh resident (24 strips VGPR + 8 strips LDS),
//                1000-step loop, h canonical fp32 in regs, bf16 h-pack in LDS rebuilt per step.

typedef __bf16 bf16;
typedef __bf16 bf16x8 __attribute__((ext_vector_type(8)));
typedef float floatx4 __attribute__((ext_vector_type(4)));
typedef unsigned short u16;
typedef u16 u16x4 __attribute__((ext_vector_type(4)));

#define T_STEPS 1000
#define BATCH 256
#define NDIM 512
#define IDIM 128

// ---------------- Phase 0: pack weights into fragment layout ----------------
// Whpack entry e (16B): g=e>>10 (0..31), s=(e>>6)&15, lane=e&63
//   holds W_hh[16g + (lane&15)][32s + 8*(lane>>4) + j], j=0..7 (bf16)
// Win pack entry e2 (16B): g=e2>>8 (0..31), s=(e2>>6)&3, lane=e2&63
//   holds W_in[16g + (lane&15)][32s + 8*(lane>>4) + j]  (hi and lo = residual)
__global__ void pack_kernel(const float* __restrict__ W_hh,
                            const float* __restrict__ W_in,
                            bf16x8* __restrict__ Whpack,
                            bf16x8* __restrict__ WinHi,
                            bf16x8* __restrict__ WinLo) {
    int e = blockIdx.x * 256 + threadIdx.x;
    if (e < 32768) {
        int g = e >> 10, s = (e >> 6) & 15, lane = e & 63;
        int n = 16 * g + (lane & 15);
        int k = 32 * s + 8 * (lane >> 4);
        const float* src = W_hh + n * 512 + k;
        bf16x8 v;
#pragma unroll
        for (int j = 0; j < 8; j++) v[j] = (bf16)src[j];
        Whpack[e] = v;
    } else {
        int e2 = e - 32768;
        if (e2 < 8192) {
            int g = e2 >> 8, s = (e2 >> 6) & 3, lane = e2 & 63;
            int n = 16 * g + (lane & 15);
            int i = 32 * s + 8 * (lane >> 4);
            const float* src = W_in + n * 128 + i;
            bf16x8 vh, vl;
#pragma unroll
            for (int j = 0; j < 8; j++) {
                float w = src[j];
                bf16 h = (bf16)w;
                vh[j] = h;
                vl[j] = (bf16)(w - (float)h);
            }
            WinHi[e2] = vh;
            WinLo[e2] = vl;
        }
    }
}

// ---------------- Phase 1: xproj = x @ W_in^T + b_in (3-term split-bf16) ----------------
// grid 4000 x 256. Each wave owns one 16-row M-tile of the [256000 x 512] output.
// MFMA roles: A = x rows (M), B = W_in rows (N). D: col(lane&15)=n, row=(lane>>4)*4+reg = r.
__global__ __launch_bounds__(256)
void xproj_kernel(const float* __restrict__ x,
                  const float* __restrict__ b_in,
                  const bf16x8* __restrict__ WinHi,
                  const bf16x8* __restrict__ WinLo,
                  float* __restrict__ out) {
    int wave = threadIdx.x >> 6, lane = threadIdx.x & 63;
    int m = lane & 15, q = lane >> 4;
    long Mtile = (long)blockIdx.x * 4 + wave;
    long r0 = Mtile * 16;

    // A fragments: lane holds x[r0+m][32s + 8q + j], hi/lo split
    bf16x8 ah[4], al[4];
    const float* xrow = x + (r0 + m) * IDIM + q * 8;
#pragma unroll
    for (int s = 0; s < 4; s++) {
#pragma unroll
        for (int j = 0; j < 8; j++) {
            float w = xrow[s * 32 + j];
            bf16 h = (bf16)w;
            ah[s][j] = h;
            al[s][j] = (bf16)(w - (float)h);
        }
    }
    float* orow = out + r0 * NDIM;
#pragma unroll 1
    for (int g = 0; g < 32; g++) {
        floatx4 acc = {0.f, 0.f, 0.f, 0.f};
#pragma unroll
        for (int s = 0; s < 4; s++) {
            bf16x8 bh = WinHi[(g * 4 + s) * 64 + lane];
            bf16x8 bl = WinLo[(g * 4 + s) * 64 + lane];
            acc = __builtin_amdgcn_mfma_f32_16x16x32_bf16(ah[s], bh, acc, 0, 0, 0);
            acc = __builtin_amdgcn_mfma_f32_16x16x32_bf16(al[s], bh, acc, 0, 0, 0);
            acc = __builtin_amdgcn_mfma_f32_16x16x32_bf16(ah[s], bl, acc, 0, 0, 0);
        }
        float b = b_in[16 * g + m];
#pragma unroll
        for (int r = 0; r < 4; r++) {
            orow[(long)(q * 4 + r) * NDIM + 16 * g + m] = acc[r] + b;
        }
    }
}

// ---------------- Phase 2: the sequential scan ----------------
// 16 WGs x 256 threads (4 waves). WG owns batches [16*blk, 16*blk+16).
// Wave w owns output strips (n-tiles of 16) gstrip = 8w..8w+7:
//   strips 8w..8w+5 : W fragments resident in VGPRs (6*16 bf16x8 = 384 VGPRs/lane)
//   strips 8w+6,8w+7: W fragments in LDS (8 strips * 16KB = 128KB)
// pack (LDS, 16KB): pack[s][lane] = h_t[b0+(lane&15)][32s + 8*(lane>>4) + j] bf16.
// MFMA: A = W strip rows (M-role = n), B = h frag (N-role = batch).
// D: col(lane&15) = batch m, row = q*4+reg = n within strip.
__global__ __launch_bounds__(256, 1)
void scan_kernel(const float* __restrict__ h0,
                 const bf16x8* __restrict__ Whpack,
                 float* __restrict__ out) {
    extern __shared__ char smem[];
    bf16x8* Wlds = (bf16x8*)smem;                    // 8192 entries = 128KB
    bf16x8* pack = (bf16x8*)(smem + 128 * 1024);     // 1024 entries = 16KB

    const int tid = threadIdx.x;
    const int wave = tid >> 6, lane = tid & 63;
    const int m = lane & 15, q = lane >> 4;
    const int b0 = blockIdx.x * 16;

    // --- load register-resident W strips (global strips 8w .. 8w+5)
    bf16x8 Wr[6][16];
    {
        const bf16x8* base = Whpack + (8 * wave) * 1024 + lane;
#pragma unroll
        for (int i = 0; i < 6; i++)
#pragma unroll
            for (int s = 0; s < 16; s++)
                Wr[i][s] = base[(i * 16 + s) * 64];
    }
    // --- cooperative load of LDS-resident strips (slot = 2w+l <-> global 8w+6+l)
    for (int r = 0; r < 32; r++) {
        int e = r * 256 + tid;
        int slot = e >> 10;
        int rem = e & 1023;
        int gs = 8 * (slot >> 1) + 6 + (slot & 1);
        Wlds[e] = Whpack[gs * 1024 + rem];
    }
    // --- init canonical h (fp32, regs) and bf16 pack from h0
    floatx4 h32[8];
#pragma unroll
    for (int i = 0; i < 8; i++) {
        int n0 = (8 * wave + i) * 16 + q * 4;
        h32[i] = *(const floatx4*)(h0 + (b0 + m) * NDIM + n0);
    }
#pragma unroll
    for (int si = 0; si < 4; si++) {
        int s = 4 * wave + si;
        const float* src = h0 + (b0 + m) * NDIM + s * 32 + q * 8;
        bf16x8 v;
#pragma unroll
        for (int j = 0; j < 8; j++) v[j] = (bf16)src[j];
        pack[s * 64 + lane] = v;
    }
    __syncthreads();

    const int wslot0 = (2 * wave) * 1024;
    const int wslot1 = (2 * wave + 1) * 1024;

#pragma unroll 1
    for (int t = 0; t < T_STEPS; t++) {
        floatx4 acc[8];
#pragma unroll
        for (int i = 0; i < 8; i++) acc[i] = (floatx4){0.f, 0.f, 0.f, 0.f};

#pragma unroll
        for (int s = 0; s < 16; s++) {
            bf16x8 hfrag = pack[s * 64 + lane];
#pragma unroll
            for (int i = 0; i < 6; i++)
                acc[i] = __builtin_amdgcn_mfma_f32_16x16x32_bf16(Wr[i][s], hfrag, acc[i], 0, 0, 0);
            bf16x8 wl0 = Wlds[wslot0 + s * 64 + lane];
            acc[6] = __builtin_amdgcn_mfma_f32_16x16x32_bf16(wl0, hfrag, acc[6], 0, 0, 0);
            bf16x8 wl1 = Wlds[wslot1 + s * 64 + lane];
            acc[7] = __builtin_amdgcn_mfma_f32_16x16x32_bf16(wl1, hfrag, acc[7], 0, 0, 0);
        }
        __syncthreads();   // everyone done reading pack (h_{t-1})

        // epilogue: h_t = 0.8*h + 0.2*tanh(xp + y);  xp lives in out[t] (xproj), overwritten with h_t
        float* row = out + ((long)(t * BATCH + b0 + m)) * NDIM;
#pragma unroll
        for (int i = 0; i < 8; i++) {
            int n0 = (8 * wave + i) * 16 + q * 4;
            floatx4 xp = *(const floatx4*)(row + n0);
            floatx4 z = xp + acc[i];
            floatx4 hn;
#pragma unroll
            for (int r = 0; r < 4; r++) {
                // tanh(x) = 1 - 2/(1+exp2(x*2*log2(e))); inf/0 endpoints give +-1 correctly
                float e = __builtin_amdgcn_exp2f(z[r] * 2.885390081777927f);
                hn[r] = 1.0f - 2.0f * __builtin_amdgcn_rcpf(e + 1.0f);
            }
            h32[i] = h32[i] * 0.8f + hn * 0.2f;
            *(floatx4*)(row + n0) = h32[i];
            // write 4 bf16 into pack for next step: global k = n0..n0+3
            int sp = n0 >> 5;
            int o = (n0 >> 3) & 3;
            u16x4 pw;
#pragma unroll
            for (int r = 0; r < 4; r++) {
                bf16 hb = (bf16)h32[i][r];
                pw[r] = __builtin_bit_cast(u16, hb);
            }
            *(u16x4*)(((char*)pack) + (sp * 64 + m + 16 * o) * 16 + (n0 & 7) * 2) = pw;
        }
        __syncthreads();   // pack (h_t) complete before next k-loop
    }

    // final hidden state
    float* hid = out + (long)T_STEPS * BATCH * NDIM;
#pragma unroll
    for (int i = 0; i < 8; i++) {
        int n0 = (8 * wave + i) * 16 + q * 4;
        *(floatx4*)(hid + (b0 + m) * NDIM + n0) = h32[i];
    }
}

extern "C" void kernel_launch(void* const* d_in, const int* in_sizes, int n_in,
                              void* d_out, int out_size, void* d_ws, size_t ws_size,
                              hipStream_t stream) {
    const float* x    = (const float*)d_in[0];
    const float* h0   = (const float*)d_in[1];
    const float* W_in = (const float*)d_in[2];
    const float* b_in = (const float*)d_in[3];
    const float* W_hh = (const float*)d_in[4];
    float* out = (float*)d_out;

    // workspace carve: Whpack 512KB | WinHi 128KB | WinLo 128KB  (total 768KB)
    bf16x8* Whpack = (bf16x8*)d_ws;
    bf16x8* WinHi  = (bf16x8*)((char*)d_ws + 524288);
    bf16x8* WinLo  = (bf16x8*)((char*)d_ws + 655360);

    static bool attr_set = false;
    (void)attr_set;
    hipFuncSetAttribute((const void*)scan_kernel,
                        hipFuncAttributeMaxDynamicSharedMemorySize, 147456);

    pack_kernel<<<160, 256, 0, stream>>>(W_hh, W_in, Whpack, WinHi, WinLo);
    xproj_kernel<<<4000, 256, 0, stream>>>(x, b_in, WinHi, WinLo, out);
    scan_kernel<<<16, 256, 147456, stream>>>(h0, Whpack, out);
}

// Round 2
// 4130.899 us; speedup vs baseline: 1.5757x; 1.5757x over previous
//
#include <hip/hip_runtime.h>
#include <hip/hip_bf16.h>

// CTRNN: T=1000, B=256, I=128, N=512, ALPHA=0.2
// d_in: x[1000,256,128] f32, h0[256,512] f32, W_in[512,128] f32, b_in[512] f32, W_hh[512,512] f32
// d_out: output[1000,256,512] f32 ++ hidden[256,512] f32
//
//  pack_kernel : W_hh -> bf16 MFMA-A-fragment layout (512KB); W_in -> hi/lo bf16 frags in d_ws
//  xproj_kernel: xproj = x @ W_in^T + b_in via 3-term split-bf16 MFMA, written INTO d_out
//  scan_kernel : 16 WGs x 512 threads (8 waves). Wave owns 4 n-strips: 3 in VGPR (192 regs),
//                1 in LDS (8 strips = 128KB) -- fits the 256-reg/wave budget at 2 waves/SIMD
//                (round-1 failure: 6 strips/wave = 384 regs > 256 arch ceiling -> scratch spill).

typedef __bf16 bf16;
typedef __bf16 bf16x8 __attribute__((ext_vector_type(8)));
typedef float floatx4 __attribute__((ext_vector_type(4)));
typedef unsigned short u16;
typedef u16 u16x4 __attribute__((ext_vector_type(4)));

#define T_STEPS 1000
#define BATCH 256
#define NDIM 512
#define IDIM 128

// ---------------- Phase 0: pack weights into fragment layout ----------------
// Whpack entry e (16B): g=e>>10 (0..31), s=(e>>6)&15, lane=e&63
//   holds W_hh[16g + (lane&15)][32s + 8*(lane>>4) + j], j=0..7 (bf16)
// Win pack entry e2 (16B): g=e2>>8 (0..31), s=(e2>>6)&3, lane=e2&63
//   holds W_in[16g + (lane&15)][32s + 8*(lane>>4) + j]  (hi and lo = residual)
__global__ void pack_kernel(const float* __restrict__ W_hh,
                            const float* __restrict__ W_in,
                            bf16x8* __restrict__ Whpack,
                            bf16x8* __restrict__ WinHi,
                            bf16x8* __restrict__ WinLo) {
    int e = blockIdx.x * 256 + threadIdx.x;
    if (e < 32768) {
        int g = e >> 10, s = (e >> 6) & 15, lane = e & 63;
        int n = 16 * g + (lane & 15);
        int k = 32 * s + 8 * (lane >> 4);
        const float* src = W_hh + n * 512 + k;
        bf16x8 v;
#pragma unroll
        for (int j = 0; j < 8; j++) v[j] = (bf16)src[j];
        Whpack[e] = v;
    } else {
        int e2 = e - 32768;
        if (e2 < 8192) {
            int g = e2 >> 8, s = (e2 >> 6) & 3, lane = e2 & 63;
            int n = 16 * g + (lane & 15);
            int i = 32 * s + 8 * (lane >> 4);
            const float* src = W_in + n * 128 + i;
            bf16x8 vh, vl;
#pragma unroll
            for (int j = 0; j < 8; j++) {
                float w = src[j];
                bf16 h = (bf16)w;
                vh[j] = h;
                vl[j] = (bf16)(w - (float)h);
            }
            WinHi[e2] = vh;
            WinLo[e2] = vl;
        }
    }
}

// ---------------- Phase 1: xproj = x @ W_in^T + b_in (3-term split-bf16) ----------------
__global__ __launch_bounds__(256)
void xproj_kernel(const float* __restrict__ x,
                  const float* __restrict__ b_in,
                  const bf16x8* __restrict__ WinHi,
                  const bf16x8* __restrict__ WinLo,
                  float* __restrict__ out) {
    int wave = threadIdx.x >> 6, lane = threadIdx.x & 63;
    int m = lane & 15, q = lane >> 4;
    long Mtile = (long)blockIdx.x * 4 + wave;
    long r0 = Mtile * 16;

    bf16x8 ah[4], al[4];
    const float* xrow = x + (r0 + m) * IDIM + q * 8;
#pragma unroll
    for (int s = 0; s < 4; s++) {
#pragma unroll
        for (int j = 0; j < 8; j++) {
            float w = xrow[s * 32 + j];
            bf16 h = (bf16)w;
            ah[s][j] = h;
            al[s][j] = (bf16)(w - (float)h);
        }
    }
    float* orow = out + r0 * NDIM;
#pragma unroll 1
    for (int g = 0; g < 32; g++) {
        floatx4 acc = {0.f, 0.f, 0.f, 0.f};
#pragma unroll
        for (int s = 0; s < 4; s++) {
            bf16x8 bh = WinHi[(g * 4 + s) * 64 + lane];
            bf16x8 bl = WinLo[(g * 4 + s) * 64 + lane];
            acc = __builtin_amdgcn_mfma_f32_16x16x32_bf16(ah[s], bh, acc, 0, 0, 0);
            acc = __builtin_amdgcn_mfma_f32_16x16x32_bf16(al[s], bh, acc, 0, 0, 0);
            acc = __builtin_amdgcn_mfma_f32_16x16x32_bf16(ah[s], bl, acc, 0, 0, 0);
        }
        float b = b_in[16 * g + m];
#pragma unroll
        for (int r = 0; r < 4; r++) {
            orow[(long)(q * 4 + r) * NDIM + 16 * g + m] = acc[r] + b;
        }
    }
}

// ---------------- Phase 2: the sequential scan (8 waves / WG) ----------------
// 16 WGs x 512 threads. WG owns batches [16*blk, 16*blk+16).
// Wave w (0..7) owns n-strips 4w..4w+3 (n = 64w .. 64w+63):
//   strips 4w..4w+2 : W fragments in VGPRs (3*16 bf16x8 = 192 regs/lane)
//   strip  4w+3     : W fragments in LDS slot w (8 strips * 16KB = 128KB)
// pack (LDS, 16KB): pack[s*64+lane] = h_t[b0+(lane&15)][32s + 8*(lane>>4) + j] bf16.
// MFMA: A = W strip rows (M-role = n), B = h frag (N-role = batch).
// D: col(lane&15) = batch m, row = q*4+reg = n within strip.
__global__ __launch_bounds__(512, 2)
void scan_kernel(const float* __restrict__ h0,
                 const bf16x8* __restrict__ Whpack,
                 float* __restrict__ out) {
    extern __shared__ char smem[];
    bf16x8* Wlds = (bf16x8*)smem;                    // 8192 entries = 128KB
    bf16x8* pack = (bf16x8*)(smem + 128 * 1024);     // 1024 entries = 16KB

    const int tid = threadIdx.x;
    const int wave = tid >> 6, lane = tid & 63;
    const int m = lane & 15, q = lane >> 4;
    const int b0 = blockIdx.x * 16;

    // --- register-resident W strips: global strips 4w, 4w+1, 4w+2
    bf16x8 Wr[3][16];
    {
        const bf16x8* base = Whpack + (4 * wave) * 1024 + lane;
#pragma unroll
        for (int i = 0; i < 3; i++)
#pragma unroll
            for (int s = 0; s < 16; s++)
                Wr[i][s] = base[(i * 16 + s) * 64];
    }
    // --- cooperative load of LDS strips: slot w <-> global strip 4w+3
    for (int r = 0; r < 16; r++) {
        int e = r * 512 + tid;
        int slot = e >> 10;
        int rem = e & 1023;
        Wlds[e] = Whpack[(4 * slot + 3) * 1024 + rem];
    }
    // --- init canonical h (fp32, regs): wave's 4 strips
    floatx4 h32[4];
#pragma unroll
    for (int i = 0; i < 4; i++) {
        int n0 = (4 * wave + i) * 16 + q * 4;
        h32[i] = *(const floatx4*)(h0 + (b0 + m) * NDIM + n0);
    }
    // --- init bf16 pack from h0 (1024 entries, 512 threads -> 2 each)
    for (int e = tid; e < 1024; e += 512) {
        int s = e >> 6, l = e & 63;
        const float* src = h0 + (b0 + (l & 15)) * NDIM + s * 32 + 8 * (l >> 4);
        bf16x8 v;
#pragma unroll
        for (int j = 0; j < 8; j++) v[j] = (bf16)src[j];
        pack[e] = v;
    }
    __syncthreads();

    const int wslot = wave * 1024;

#pragma unroll 1
    for (int t = 0; t < T_STEPS; t++) {
        float* row = out + ((long)(t * BATCH + b0 + m)) * NDIM;
        // prefetch xp (xproj phase wrote it into out[t]); latency hides under MFMAs
        floatx4 xp[4];
#pragma unroll
        for (int i = 0; i < 4; i++) {
            int n0 = (4 * wave + i) * 16 + q * 4;
            xp[i] = *(const floatx4*)(row + n0);
        }

        floatx4 acc[4];
#pragma unroll
        for (int i = 0; i < 4; i++) acc[i] = (floatx4){0.f, 0.f, 0.f, 0.f};

#pragma unroll
        for (int s = 0; s < 16; s++) {
            bf16x8 hfrag = pack[s * 64 + lane];
#pragma unroll
            for (int i = 0; i < 3; i++)
                acc[i] = __builtin_amdgcn_mfma_f32_16x16x32_bf16(Wr[i][s], hfrag, acc[i], 0, 0, 0);
            bf16x8 wl = Wlds[wslot + s * 64 + lane];
            acc[3] = __builtin_amdgcn_mfma_f32_16x16x32_bf16(wl, hfrag, acc[3], 0, 0, 0);
        }
        __syncthreads();   // all waves done reading pack (h_{t-1})

        // epilogue: h_t = 0.8*h + 0.2*tanh(xp + y); h_t overwrites xp in out[t]
#pragma unroll
        for (int i = 0; i < 4; i++) {
            int n0 = (4 * wave + i) * 16 + q * 4;
            floatx4 z = xp[i] + acc[i];
            floatx4 hn;
#pragma unroll
            for (int r = 0; r < 4; r++) {
                // tanh(x) = 1 - 2/(1+exp2(2x*log2 e)); endpoints give +-1 correctly
                float e = __builtin_amdgcn_exp2f(z[r] * 2.885390081777927f);
                hn[r] = 1.0f - 2.0f * __builtin_amdgcn_rcpf(e + 1.0f);
            }
            h32[i] = h32[i] * 0.8f + hn * 0.2f;
            *(floatx4*)(row + n0) = h32[i];
            // write 4 bf16 into pack for next step: global k = n0..n0+3
            int sp = n0 >> 5;
            int o = (n0 >> 3) & 3;
            u16x4 pw;
#pragma unroll
            for (int r = 0; r < 4; r++) {
                bf16 hb = (bf16)h32[i][r];
                pw[r] = __builtin_bit_cast(u16, hb);
            }
            *(u16x4*)(((char*)pack) + (sp * 64 + m + 16 * o) * 16 + (n0 & 7) * 2) = pw;
        }
        __syncthreads();   // pack (h_t) complete before next k-loop
    }

    // final hidden state
    float* hid = out + (long)T_STEPS * BATCH * NDIM;
#pragma unroll
    for (int i = 0; i < 4; i++) {
        int n0 = (4 * wave + i) * 16 + q * 4;
        *(floatx4*)(hid + (b0 + m) * NDIM + n0) = h32[i];
    }
}

extern "C" void kernel_launch(void* const* d_in, const int* in_sizes, int n_in,
                              void* d_out, int out_size, void* d_ws, size_t ws_size,
                              hipStream_t stream) {
    const float* x    = (const float*)d_in[0];
    const float* h0   = (const float*)d_in[1];
    const float* W_in = (const float*)d_in[2];
    const float* b_in = (const float*)d_in[3];
    const float* W_hh = (const float*)d_in[4];
    float* out = (float*)d_out;

    // workspace carve: Whpack 512KB | WinHi 128KB | WinLo 128KB  (total 768KB)
    bf16x8* Whpack = (bf16x8*)d_ws;
    bf16x8* WinHi  = (bf16x8*)((char*)d_ws + 524288);
    bf16x8* WinLo  = (bf16x8*)((char*)d_ws + 655360);

    hipFuncSetAttribute((const void*)scan_kernel,
                        hipFuncAttributeMaxDynamicSharedMemorySize, 147456);

    pack_kernel<<<160, 256, 0, stream>>>(W_hh, W_in, Whpack, WinHi, WinLo);
    xproj_kernel<<<4000, 256, 0, stream>>>(x, b_in, WinHi, WinLo, out);
    scan_kernel<<<16, 512, 147456, stream>>>(h0, Whpack, out);
}